// Round 1
// 258.814 us; speedup vs baseline: 1.0826x; 1.0826x over previous
//
#include <hip/hip_runtime.h>
#include <hip/hip_fp16.h>
#include <math.h>

#define IN_D 64
#define HID_D 128
#define OUT_D 64

typedef _Float16 half8 __attribute__((ext_vector_type(8)));
typedef float f32x4 __attribute__((ext_vector_type(4)));

// ---------------------------------------------------------------------------
// Decode edge_index (robust to int32 or int64 storage) + int in-degree histogram
__global__ void k_decode(const unsigned int* __restrict__ raw, int E,
                         int* __restrict__ src, int* __restrict__ dst,
                         int* __restrict__ deg) {
    __shared__ int is64;
    if (threadIdx.x == 0) {
        int f = 1;
        for (int i = 1; i < 64; i += 2) f &= (raw[i] == 0u);
        is64 = f;
    }
    __syncthreads();
    int e = blockIdx.x * blockDim.x + threadIdx.x;
    if (e >= E) return;
    int s, d;
    if (is64) {
        s = (int)raw[2 * (size_t)e];
        d = (int)raw[2 * ((size_t)E + e)];
    } else {
        s = (int)raw[e];
        d = (int)raw[E + e];
    }
    src[e] = s;
    dst[e] = d;
    atomicAdd(&deg[d], 1);
}

// ---------------------------------------------------------------------------
// Exclusive scan of deg -> row_ptr
__global__ void k_scanA(const int* __restrict__ deg, int* __restrict__ part,
                        int* __restrict__ blksum, int N) {
    int i = blockIdx.x * 256 + threadIdx.x;
    int v = (i < N) ? deg[i] : 0;
    int lane = threadIdx.x & 63, w = threadIdx.x >> 6;
    for (int off = 1; off < 64; off <<= 1) {
        int n = __shfl_up(v, off);
        if (lane >= off) v += n;
    }
    __shared__ int wsum[4];
    if (lane == 63) wsum[w] = v;
    __syncthreads();
    for (int k = 0; k < w; ++k) v += wsum[k];
    if (i < N) part[i] = v;
    if (threadIdx.x == 255) blksum[blockIdx.x] = v;
}

__global__ void k_scanB(int* __restrict__ blksum, int nb) {
    int t = threadIdx.x;  // 512 threads, nb <= 512
    int v = (t < nb) ? blksum[t] : 0;
    int orig = v;
    int lane = t & 63, w = t >> 6;
    for (int off = 1; off < 64; off <<= 1) {
        int n = __shfl_up(v, off);
        if (lane >= off) v += n;
    }
    __shared__ int wsum[8];
    if (lane == 63) wsum[w] = v;
    __syncthreads();
    for (int k = 0; k < w; ++k) v += wsum[k];
    if (t < nb) blksum[t] = v - orig;
}

// row_ptr, dinv, and per-bucket base cursors (bucket = dst>>9)
__global__ void k_scanC(const int* __restrict__ deg, const int* __restrict__ part,
                        const int* __restrict__ blksum, int* __restrict__ row_ptr,
                        int* __restrict__ bcur, float* __restrict__ dinv,
                        int N, int E) {
    int i = blockIdx.x * 256 + threadIdx.x;
    if (i == 0) row_ptr[N] = E;
    if (i >= N) return;
    int start = part[i] - deg[i] + blksum[blockIdx.x];
    row_ptr[i] = start;
    if ((i & 511) == 0) bcur[i >> 9] = start;
    dinv[i] = rsqrtf((float)deg[i] + 1.0f);  // +1 = self loop
}

// ---------------------------------------------------------------------------
// Phase A: partition edges into coarse dst-buckets (512 nodes each).
#define CHUNK 2048
__global__ __launch_bounds__(256) void k_part(const int* __restrict__ src,
                                              const int* __restrict__ dst,
                                              int* __restrict__ bcur,
                                              int2* __restrict__ pairs, int E) {
    __shared__ int hist[256];
    __shared__ int base[256];
    __shared__ int cnt[256];
    for (int i = threadIdx.x; i < 256; i += 256) { hist[i] = 0; cnt[i] = 0; }
    __syncthreads();
    int e0 = blockIdx.x * CHUNK;
    int s[8], d[8], b[8];
#pragma unroll
    for (int i = 0; i < 8; ++i) {
        int e = e0 + threadIdx.x + i * 256;
        if (e < E) {
            s[i] = src[e]; d[i] = dst[e]; b[i] = d[i] >> 9;
            atomicAdd(&hist[b[i]], 1);
        } else b[i] = -1;
    }
    __syncthreads();
    if (hist[threadIdx.x] > 0)
        base[threadIdx.x] = atomicAdd(&bcur[threadIdx.x], hist[threadIdx.x]);
    __syncthreads();
#pragma unroll
    for (int i = 0; i < 8; ++i) {
        if (b[i] >= 0) {
            int pos = base[b[i]] + atomicAdd(&cnt[b[i]], 1);
            pairs[pos] = make_int2(s[i], d[i]);
        }
    }
}

// Phase B: one block per bucket; LDS cursors; confined writes.
__global__ __launch_bounds__(256) void k_place2(const int2* __restrict__ pairs,
                                                const int* __restrict__ row_ptr,
                                                int* __restrict__ csr_src, int N) {
    __shared__ int cur[512];
    int b = blockIdx.x;
    int n0 = b << 9;
    int n1 = n0 + 512; if (n1 > N) n1 = N;
    for (int j = threadIdx.x; j < n1 - n0; j += 256) cur[j] = row_ptr[n0 + j];
    __syncthreads();
    int beg = row_ptr[n0], end = row_ptr[n1];
    for (int i = beg + threadIdx.x; i < end; i += 256) {
        int2 r = pairs[i];
        int pos = atomicAdd(&cur[r.y - n0], 1);
        csr_src[pos] = r.x;
    }
}

// ---------------------------------------------------------------------------
// xs[i,:] = fp16( dinv[i] * x[i,:] ), row-major
__global__ void k_xconv(const float* __restrict__ x, const float* __restrict__ dinv,
                        __half* __restrict__ xs, int N) {
    int idx = blockIdx.x * blockDim.x + threadIdx.x;
    if (idx >= N * 32) return;
    int i = idx >> 5, c = (idx & 31) * 2;
    float di = dinv[i];
    float2 v = *(const float2*)&x[(size_t)i * 64 + c];
    *(__half2*)&xs[(size_t)i * 64 + c] = __floats2half2_rn(v.x * di, v.y * di);
}

// ---------------------------------------------------------------------------
// Pre-pack W1 (A-operand layout) and W2 (B-operand layout) into MFMA fragment order.
__global__ void k_wconv(const float* __restrict__ W1, const float* __restrict__ W2,
                        __half* __restrict__ w1f, __half* __restrict__ w2f) {
    int t = blockIdx.x * 256 + threadIdx.x;  // 0..2047
    if (t >= 2048) return;
    int which = t >> 10;
    int fl = t & 1023;
    int f = fl >> 6, l = fl & 63;
    int q = l >> 4, n16 = l & 15;
    if (which == 0) {
        int nt = f >> 1, kc = f & 1;
        int n = nt * 16 + n16;
        int k0 = kc * 32 + q * 8;
        for (int j = 0; j < 8; ++j)
            w1f[(size_t)fl * 8 + j] = __float2half(W1[(k0 + j) * 128 + n]);
    } else {
        int nt = f >> 2, kc = f & 3;
        int n = nt * 16 + n16;
        int k0 = kc * 32 + q * 8;
        for (int j = 0; j < 8; ++j)
            w2f[(size_t)fl * 8 + j] = __float2half(W2[(k0 + j) * 64 + n]);
    }
}

// ---------------------------------------------------------------------------
// Layer-1 gather: wave = 4 nodes x (2 slots x 8 col-segments), 16 B loads.
// Per loop iteration the wave has 8 independent neighbor rows in flight
// (16 with the unroll), vs ~2 for the old 1-node-per-wave layout. Self row
// + dinv hoisted to the top so their latency overlaps the neighbor loop.
// agg[node,:] = fp16( dinv * (self + sum nbrs) )   (xs pre-scaled by dinv[src])
__global__ __launch_bounds__(256) void k_gather1(const __half* __restrict__ xs,
                          const float* __restrict__ dinv,
                          const int* __restrict__ row_ptr, const int* __restrict__ csr,
                          __half* __restrict__ agg, int N) {
    int wv = threadIdx.x >> 6, l = threadIdx.x & 63;
    int ns = l >> 4;           // node-sub 0..3
    int slot = (l >> 3) & 1;   // 0..1
    int seg = l & 7;           // 0..7
    int node = (blockIdx.x * 4 + wv) * 4 + ns;
    bool valid = node < N;
    int nc = valid ? node : N - 1;
    int beg = row_ptr[nc];
    int end = valid ? row_ptr[nc + 1] : beg;
    float di = dinv[nc];
    half8 hs = *(const half8*)&xs[(size_t)nc * 64 + seg * 8];
    float acc[8];
#pragma unroll
    for (int j = 0; j < 8; ++j) acc[j] = 0.f;
    int k = beg + slot;
    for (; k + 2 < end; k += 4) {
        int s0 = csr[k], s1 = csr[k + 2];
        half8 h0 = *(const half8*)&xs[(size_t)s0 * 64 + seg * 8];
        half8 h1 = *(const half8*)&xs[(size_t)s1 * 64 + seg * 8];
#pragma unroll
        for (int j = 0; j < 8; ++j) acc[j] += (float)h0[j] + (float)h1[j];
    }
    if (k < end) {
        int s0 = csr[k];
        half8 h0 = *(const half8*)&xs[(size_t)s0 * 64 + seg * 8];
#pragma unroll
        for (int j = 0; j < 8; ++j) acc[j] += (float)h0[j];
    }
#pragma unroll
    for (int j = 0; j < 8; ++j) acc[j] += __shfl_xor(acc[j], 8);
    if (slot == 0 && valid) {
        half8 o;
#pragma unroll
        for (int j = 0; j < 8; ++j) o[j] = (_Float16)((acc[j] + (float)hs[j]) * di);
        *(half8*)&agg[(size_t)node * 64 + seg * 8] = o;
    }
}

// Layer-2 gather fused with +b2, relu, and both Wc dot products.
// Same 4-node x 2-slot x 8-seg wave layout as k_gather1.
__global__ __launch_bounds__(256) void k_gather2(const __half* __restrict__ ts,
                          const float* __restrict__ dinv,
                          const int* __restrict__ row_ptr, const int* __restrict__ csr,
                          const float* __restrict__ b2, const float* __restrict__ Wc,
                          float* __restrict__ s0o, float* __restrict__ s1o, int N) {
    int wv = threadIdx.x >> 6, l = threadIdx.x & 63;
    int ns = l >> 4;
    int slot = (l >> 3) & 1;
    int seg = l & 7;
    int node = (blockIdx.x * 4 + wv) * 4 + ns;
    bool valid = node < N;
    int nc = valid ? node : N - 1;
    int beg = row_ptr[nc];
    int end = valid ? row_ptr[nc + 1] : beg;
    float di = dinv[nc];
    half8 hs = *(const half8*)&ts[(size_t)nc * 64 + seg * 8];
    float acc[8];
#pragma unroll
    for (int j = 0; j < 8; ++j) acc[j] = 0.f;
    int k = beg + slot;
    for (; k + 2 < end; k += 4) {
        int s0 = csr[k], s1 = csr[k + 2];
        half8 h0 = *(const half8*)&ts[(size_t)s0 * 64 + seg * 8];
        half8 h1 = *(const half8*)&ts[(size_t)s1 * 64 + seg * 8];
#pragma unroll
        for (int j = 0; j < 8; ++j) acc[j] += (float)h0[j] + (float)h1[j];
    }
    if (k < end) {
        int s0 = csr[k];
        half8 h0 = *(const half8*)&ts[(size_t)s0 * 64 + seg * 8];
#pragma unroll
        for (int j = 0; j < 8; ++j) acc[j] += (float)h0[j];
    }
#pragma unroll
    for (int j = 0; j < 8; ++j) acc[j] += __shfl_xor(acc[j], 8);
    if (slot == 0) {
        float4 b2a = *(const float4*)&b2[seg * 8];
        float4 b2b = *(const float4*)&b2[seg * 8 + 4];
        float4 w0a = *(const float4*)&Wc[seg * 8];
        float4 w0b = *(const float4*)&Wc[seg * 8 + 4];
        float4 w1a = *(const float4*)&Wc[64 + seg * 8];
        float4 w1b = *(const float4*)&Wc[64 + seg * 8 + 4];
        float bb[8] = {b2a.x, b2a.y, b2a.z, b2a.w, b2b.x, b2b.y, b2b.z, b2b.w};
        float w0[8] = {w0a.x, w0a.y, w0a.z, w0a.w, w0b.x, w0b.y, w0b.z, w0b.w};
        float w1[8] = {w1a.x, w1a.y, w1a.z, w1a.w, w1b.x, w1b.y, w1b.z, w1b.w};
        float p0 = 0.f, p1 = 0.f;
#pragma unroll
        for (int j = 0; j < 8; ++j) {
            float v = fmaxf((acc[j] + (float)hs[j]) * di + bb[j], 0.f);
            p0 = fmaf(v, w0[j], p0);
            p1 = fmaf(v, w1[j], p1);
        }
        p0 += __shfl_xor(p0, 1); p1 += __shfl_xor(p1, 1);
        p0 += __shfl_xor(p0, 2); p1 += __shfl_xor(p1, 2);
        p0 += __shfl_xor(p0, 4); p1 += __shfl_xor(p1, 4);
        if (seg == 0 && valid) { s0o[node] = p0; s1o[node] = p1; }
    }
}

// ---------------------------------------------------------------------------
// MFMA fused MLP: ts = fp16( dinv * ( relu(agg @ W1 + b1) @ W2 ) ), row-major out
__global__ __launch_bounds__(256) void k_mlp_mfma(const __half* __restrict__ agg_h,
                                                  const __half* __restrict__ w1f,
                                                  const __half* __restrict__ w2f,
                                                  const float* __restrict__ b1,
                                                  const float* __restrict__ dinv,
                                                  __half* __restrict__ ts, int N) {
    __shared__ __align__(16) __half w1l[8192];
    __shared__ __align__(16) __half w2l[8192];
    {
        const float4* sA = (const float4*)w1f;
        const float4* sB = (const float4*)w2f;
        float4* dA = (float4*)w1l;
        float4* dB = (float4*)w2l;
        for (int i = threadIdx.x; i < 1024; i += 256) { dA[i] = sA[i]; dB[i] = sB[i]; }
    }
    __syncthreads();

    int wv = threadIdx.x >> 6, l = threadIdx.x & 63;
    int m0 = blockIdx.x * 64 + wv * 16;
    if (m0 >= N) return;
    int q = l >> 4, ml = l & 15;
    int rowA = m0 + ml; if (rowA >= N) rowA = N - 1;

    half8 bfr0 = *(const half8*)&agg_h[(size_t)rowA * 64 + q * 8];
    half8 bfr1 = *(const half8*)&agg_h[(size_t)rowA * 64 + 32 + q * 8];

    int pk[8][2];
#pragma unroll
    for (int nt = 0; nt < 8; ++nt) {
        float4 bb = *(const float4*)&b1[nt * 16 + q * 4];
        f32x4 cacc; cacc[0] = bb.x; cacc[1] = bb.y; cacc[2] = bb.z; cacc[3] = bb.w;
        half8 a0 = *(const half8*)&w1l[(nt * 2 + 0) * 512 + l * 8];
        cacc = __builtin_amdgcn_mfma_f32_16x16x32_f16(a0, bfr0, cacc, 0, 0, 0);
        half8 a1 = *(const half8*)&w1l[(nt * 2 + 1) * 512 + l * 8];
        cacc = __builtin_amdgcn_mfma_f32_16x16x32_f16(a1, bfr1, cacc, 0, 0, 0);
        union { __half2 h; int i; } u0, u1;
        u0.h = __floats2half2_rn(fmaxf(cacc[0], 0.f), fmaxf(cacc[1], 0.f));
        u1.h = __floats2half2_rn(fmaxf(cacc[2], 0.f), fmaxf(cacc[3], 0.f));
        pk[nt][0] = u0.i;
        pk[nt][1] = u1.i;
    }

    int src0 = ml + 16 * ((2 * q) & 3);
    int src1 = ml + 16 * ((2 * q + 1) & 3);
    bool hi = (q >= 2);
    half8 afr[4];
#pragma unroll
    for (int kc = 0; kc < 4; ++kc) {
        int t0 = 2 * kc, t1 = 2 * kc + 1;
        int d0a = __shfl(pk[t0][0], src0), d0b = __shfl(pk[t1][0], src0);
        int d1a = __shfl(pk[t0][1], src0), d1b = __shfl(pk[t1][1], src0);
        int d2a = __shfl(pk[t0][0], src1), d2b = __shfl(pk[t1][0], src1);
        int d3a = __shfl(pk[t0][1], src1), d3b = __shfl(pk[t1][1], src1);
        union { int d[4]; half8 h; } u;
        u.d[0] = hi ? d0b : d0a;
        u.d[1] = hi ? d1b : d1a;
        u.d[2] = hi ? d2b : d2a;
        u.d[3] = hi ? d3b : d3a;
        afr[kc] = u.h;
    }

    float dl = dinv[rowA];
    float dv[4];
#pragma unroll
    for (int r = 0; r < 4; ++r) dv[r] = __shfl(dl, q * 4 + r);

#pragma unroll
    for (int nt2 = 0; nt2 < 4; ++nt2) {
        f32x4 cacc; cacc[0] = 0.f; cacc[1] = 0.f; cacc[2] = 0.f; cacc[3] = 0.f;
#pragma unroll
        for (int kc = 0; kc < 4; ++kc) {
            half8 b = *(const half8*)&w2l[(nt2 * 4 + kc) * 512 + l * 8];
            cacc = __builtin_amdgcn_mfma_f32_16x16x32_f16(afr[kc], b, cacc, 0, 0, 0);
        }
#pragma unroll
        for (int r = 0; r < 4; ++r) {
            int node = m0 + q * 4 + r;
            if (node < N)
                ts[(size_t)node * 64 + nt2 * 16 + ml] = __float2half(cacc[r] * dv[r]);
        }
    }
}

__global__ void k_edge(const int* __restrict__ src, const int* __restrict__ dst,
                       const float* __restrict__ s0, const float* __restrict__ s1,
                       const float* __restrict__ bc, float* __restrict__ out, int E) {
    int e = blockIdx.x * blockDim.x + threadIdx.x;
    if (e >= E) return;
    float z = s0[src[e]] + s1[dst[e]] + bc[0];
    out[e] = 1.0f / (1.0f + expf(-z));
}

// ---------------------------------------------------------------------------
extern "C" void kernel_launch(void* const* d_in, const int* in_sizes, int n_in,
                              void* d_out, int out_size, void* d_ws, size_t ws_size,
                              hipStream_t stream) {
    const float* x  = (const float*)d_in[0];
    const unsigned int* eidx = (const unsigned int*)d_in[1];
    const float* W1 = (const float*)d_in[2];
    const float* b1 = (const float*)d_in[3];
    const float* W2 = (const float*)d_in[4];
    const float* b2 = (const float*)d_in[5];
    const float* Wc = (const float*)d_in[6];
    const float* bc = (const float*)d_in[7];
    float* out = (float*)d_out;

    int N = in_sizes[0] / IN_D;
    int E = in_sizes[1] / 2;
    int nblkN = (N + 255) / 256;      // 391 for N=100k (<= 512 for scanB)
    int nbuk  = (N + 511) >> 9;       // 196 buckets of 512 nodes (<= 256)

    char* p = (char*)d_ws;
    int*   src     = (int*)p;    p += (size_t)E * 4;
    int*   dst     = (int*)p;    p += (size_t)E * 4;
    int*   deg     = (int*)p;    p += (size_t)N * 4;
    int*   part    = (int*)p;    p += (size_t)N * 4;
    int*   blksum  = (int*)p;    p += 512 * 4;
    int*   bcur    = (int*)p;    p += 256 * 4;
    int*   row_ptr = (int*)p;    p += (size_t)(N + 1) * 4;
    int*   csr_src = (int*)p;    p += (size_t)E * 4;
    float* dinv    = (float*)p;  p += (size_t)N * 4;
    float* s0      = (float*)p;  p += (size_t)N * 4;
    float* s1      = (float*)p;  p += (size_t)N * 4;
    p += 15; p = (char*)((size_t)p & ~(size_t)15);
    int2*  pairs   = (int2*)p;   p += (size_t)E * 8;   // dead after k_place2
    __half* xs    = (__half*)p;  p += (size_t)N * 64 * 2;
    __half* aggh  = (__half*)p;  p += (size_t)N * 64 * 2;
    __half* ts    = (__half*)p;  p += (size_t)N * 64 * 2;
    __half* w1f   = (__half*)p;  p += 8192 * 2;
    __half* w2f   = (__half*)p;  p += 8192 * 2;

    hipMemsetAsync(deg, 0, (size_t)N * 4, stream);

    // CSR build: decode+histogram, scan, 2-phase bucketed place
    k_decode<<<(E + 255) / 256, 256, 0, stream>>>(eidx, E, src, dst, deg);
    k_wconv<<<8, 256, 0, stream>>>(W1, W2, w1f, w2f);
    k_scanA<<<nblkN, 256, 0, stream>>>(deg, part, blksum, N);
    k_scanB<<<1, 512, 0, stream>>>(blksum, nblkN);
    k_scanC<<<nblkN, 256, 0, stream>>>(deg, part, blksum, row_ptr, bcur, dinv, N, E);
    k_part<<<(E + CHUNK - 1) / CHUNK, 256, 0, stream>>>(src, dst, bcur, pairs, E);
    k_place2<<<nbuk, 256, 0, stream>>>(pairs, row_ptr, csr_src, N);

    // Pre-scaled fp16 features (row-major); layer-1 gather
    k_xconv<<<(N * 32 + 255) / 256, 256, 0, stream>>>(x, dinv, xs, N);
    k_gather1<<<(N + 15) / 16, 256, 0, stream>>>(xs, dinv, row_ptr, csr_src, aggh, N);

    // MFMA fused MLP
    k_mlp_mfma<<<(N + 63) / 64, 256, 0, stream>>>(aggh, w1f, w2f, b1, dinv, ts, N);

    // Layer-2 gather fused with b2/relu/Wc scores
    k_gather2<<<(N + 15) / 16, 256, 0, stream>>>(ts, dinv, row_ptr, csr_src,
                                                 b2, Wc, s0, s1, N);

    // Per-edge sigmoid from per-node partial scores
    k_edge<<<(E + 255) / 256, 256, 0, stream>>>(src, dst, s0, s1, bc, out, E);
}

// Round 2
// 232.778 us; speedup vs baseline: 1.2036x; 1.1119x over previous
//
#include <hip/hip_runtime.h>
#include <hip/hip_fp16.h>
#include <math.h>

#define IN_D 64
#define HID_D 128
#define OUT_D 64

typedef _Float16 half8 __attribute__((ext_vector_type(8)));
typedef float f32x4 __attribute__((ext_vector_type(4)));

// ---------------------------------------------------------------------------
// Decode edge_index (robust to int32 or int64 storage) + LDS-privatized
// bucket histogram (bucket = dst>>9). ~196 global atomics per 2048-edge block
// instead of 2048 — kills the 31 MB of scattered atomic RMW write traffic
// that made the old decode 44 us.
#define DCHUNK 2048
__global__ __launch_bounds__(256) void k_decode2(const unsigned int* __restrict__ raw,
                                                 int E,
                                                 int* __restrict__ src,
                                                 int* __restrict__ dst,
                                                 int* __restrict__ bkcnt) {
    __shared__ int hist[256];
    __shared__ int is64;
    if (threadIdx.x == 0) {
        int f = 1;
        for (int i = 1; i < 64; i += 2) f &= (raw[i] == 0u);
        is64 = f;
    }
    for (int i = threadIdx.x; i < 256; i += 256) hist[i] = 0;
    __syncthreads();
    int e0 = blockIdx.x * DCHUNK;
#pragma unroll
    for (int i = 0; i < 8; ++i) {
        int e = e0 + threadIdx.x + i * 256;
        if (e < E) {
            int s, d;
            if (is64) {
                s = (int)raw[2 * (size_t)e];
                d = (int)raw[2 * ((size_t)E + e)];
            } else {
                s = (int)raw[e];
                d = (int)raw[E + e];
            }
            src[e] = s;
            dst[e] = d;
            atomicAdd(&hist[d >> 9], 1);
        }
    }
    __syncthreads();
    if (hist[threadIdx.x] > 0)
        atomicAdd(&bkcnt[threadIdx.x], hist[threadIdx.x]);
}

// ---------------------------------------------------------------------------
// Tiny single-block exclusive scan of bucket counts -> bucket bases + cursors.
__global__ void k_bkscan(const int* __restrict__ bkcnt, int* __restrict__ bkbase,
                         int* __restrict__ bcur, int nbuk, int E) {
    int t = threadIdx.x;  // 256 threads, nbuk <= 256
    int v = (t < nbuk) ? bkcnt[t] : 0;
    int orig = v;
    int lane = t & 63, w = t >> 6;
    for (int off = 1; off < 64; off <<= 1) {
        int n = __shfl_up(v, off);
        if (lane >= off) v += n;
    }
    __shared__ int wsum[4];
    if (lane == 63) wsum[w] = v;
    __syncthreads();
    for (int k = 0; k < w; ++k) v += wsum[k];
    int base = v - orig;
    if (t < nbuk) { bkbase[t] = base; bcur[t] = base; }
    if (t == 0) bkbase[nbuk] = E;
}

// ---------------------------------------------------------------------------
// Phase A: partition edges into coarse dst-buckets (512 nodes each).
#define CHUNK 2048
__global__ __launch_bounds__(256) void k_part(const int* __restrict__ src,
                                              const int* __restrict__ dst,
                                              int* __restrict__ bcur,
                                              int2* __restrict__ pairs, int E) {
    __shared__ int hist[256];
    __shared__ int base[256];
    __shared__ int cnt[256];
    for (int i = threadIdx.x; i < 256; i += 256) { hist[i] = 0; cnt[i] = 0; }
    __syncthreads();
    int e0 = blockIdx.x * CHUNK;
    int s[8], d[8], b[8];
#pragma unroll
    for (int i = 0; i < 8; ++i) {
        int e = e0 + threadIdx.x + i * 256;
        if (e < E) {
            s[i] = src[e]; d[i] = dst[e]; b[i] = d[i] >> 9;
            atomicAdd(&hist[b[i]], 1);
        } else b[i] = -1;
    }
    __syncthreads();
    if (hist[threadIdx.x] > 0)
        base[threadIdx.x] = atomicAdd(&bcur[threadIdx.x], hist[threadIdx.x]);
    __syncthreads();
#pragma unroll
    for (int i = 0; i < 8; ++i) {
        if (b[i] >= 0) {
            int pos = base[b[i]] + atomicAdd(&cnt[b[i]], 1);
            pairs[pos] = make_int2(s[i], d[i]);
        }
    }
}

// ---------------------------------------------------------------------------
// Per-bucket CSR build: LDS per-node degree histogram -> LDS exclusive scan
// -> row_ptr + dinv + cursor init -> place csr_src. Replaces the three full-N
// scan kernels and k_place2; zero global atomics.
__global__ __launch_bounds__(256) void k_build(const int2* __restrict__ pairs,
                                               const int* __restrict__ bkbase,
                                               int* __restrict__ row_ptr,
                                               int* __restrict__ csr_src,
                                               float* __restrict__ dinv,
                                               int N, int E, int nbuk) {
    __shared__ int deg5[512];
    __shared__ int cur5[512];
    __shared__ int wsum[4];
    int b = blockIdx.x;
    int n0 = b << 9;
    int n1 = n0 + 512; if (n1 > N) n1 = N;
    int nn = n1 - n0;
    deg5[threadIdx.x] = 0;
    deg5[threadIdx.x + 256] = 0;
    __syncthreads();
    int beg = bkbase[b], end = bkbase[b + 1];
    for (int i = beg + threadIdx.x; i < end; i += 256)
        atomicAdd(&deg5[pairs[i].y - n0], 1);
    __syncthreads();
    // exclusive scan over 512 degrees, 2 elements per thread
    int t = threadIdx.x;
    int v0 = deg5[2 * t], v1 = deg5[2 * t + 1];
    int s = v0 + v1;
    int lane = t & 63, w = t >> 6;
    int inc = s;
    for (int off = 1; off < 64; off <<= 1) {
        int n = __shfl_up(inc, off);
        if (lane >= off) inc += n;
    }
    if (lane == 63) wsum[w] = inc;
    __syncthreads();
    for (int k = 0; k < w; ++k) inc += wsum[k];
    int ex0 = inc - s;   // exclusive prefix of element 2t
    int ex1 = inc - v1;  // exclusive prefix of element 2t+1
    cur5[2 * t]     = beg + ex0;
    cur5[2 * t + 1] = beg + ex1;
    if (2 * t < nn) {
        row_ptr[n0 + 2 * t] = beg + ex0;
        dinv[n0 + 2 * t] = rsqrtf((float)v0 + 1.0f);  // +1 = self loop
    }
    if (2 * t + 1 < nn) {
        row_ptr[n0 + 2 * t + 1] = beg + ex1;
        dinv[n0 + 2 * t + 1] = rsqrtf((float)v1 + 1.0f);
    }
    if (b == nbuk - 1 && t == 0) row_ptr[N] = E;
    __syncthreads();
    for (int i = beg + threadIdx.x; i < end; i += 256) {
        int2 r = pairs[i];
        int pos = atomicAdd(&cur5[r.y - n0], 1);
        csr_src[pos] = r.x;
    }
}

// ---------------------------------------------------------------------------
// xs[i,:] = fp16( dinv[i] * x[i,:] ), row-major
__global__ void k_xconv(const float* __restrict__ x, const float* __restrict__ dinv,
                        __half* __restrict__ xs, int N) {
    int idx = blockIdx.x * blockDim.x + threadIdx.x;
    if (idx >= N * 32) return;
    int i = idx >> 5, c = (idx & 31) * 2;
    float di = dinv[i];
    float2 v = *(const float2*)&x[(size_t)i * 64 + c];
    *(__half2*)&xs[(size_t)i * 64 + c] = __floats2half2_rn(v.x * di, v.y * di);
}

// ---------------------------------------------------------------------------
// Pre-pack W1 (A-operand layout) and W2 (B-operand layout) into MFMA fragment order.
__global__ void k_wconv(const float* __restrict__ W1, const float* __restrict__ W2,
                        __half* __restrict__ w1f, __half* __restrict__ w2f) {
    int t = blockIdx.x * 256 + threadIdx.x;  // 0..2047
    if (t >= 2048) return;
    int which = t >> 10;
    int fl = t & 1023;
    int f = fl >> 6, l = fl & 63;
    int q = l >> 4, n16 = l & 15;
    if (which == 0) {
        int nt = f >> 1, kc = f & 1;
        int n = nt * 16 + n16;
        int k0 = kc * 32 + q * 8;
        for (int j = 0; j < 8; ++j)
            w1f[(size_t)fl * 8 + j] = __float2half(W1[(k0 + j) * 128 + n]);
    } else {
        int nt = f >> 2, kc = f & 3;
        int n = nt * 16 + n16;
        int k0 = kc * 32 + q * 8;
        for (int j = 0; j < 8; ++j)
            w2f[(size_t)fl * 8 + j] = __float2half(W2[(k0 + j) * 64 + n]);
    }
}

// ---------------------------------------------------------------------------
// Layer-1 gather: wave = 4 nodes x (2 slots x 8 col-segments), 16 B loads.
// agg[node,:] = fp16( dinv * (self + sum nbrs) )   (xs pre-scaled by dinv[src])
__global__ __launch_bounds__(256) void k_gather1(const __half* __restrict__ xs,
                          const float* __restrict__ dinv,
                          const int* __restrict__ row_ptr, const int* __restrict__ csr,
                          __half* __restrict__ agg, int N) {
    int wv = threadIdx.x >> 6, l = threadIdx.x & 63;
    int ns = l >> 4;           // node-sub 0..3
    int slot = (l >> 3) & 1;   // 0..1
    int seg = l & 7;           // 0..7
    int node = (blockIdx.x * 4 + wv) * 4 + ns;
    bool valid = node < N;
    int nc = valid ? node : N - 1;
    int beg = row_ptr[nc];
    int end = valid ? row_ptr[nc + 1] : beg;
    float di = dinv[nc];
    half8 hs = *(const half8*)&xs[(size_t)nc * 64 + seg * 8];
    float acc[8];
#pragma unroll
    for (int j = 0; j < 8; ++j) acc[j] = 0.f;
    int k = beg + slot;
    for (; k + 2 < end; k += 4) {
        int s0 = csr[k], s1 = csr[k + 2];
        half8 h0 = *(const half8*)&xs[(size_t)s0 * 64 + seg * 8];
        half8 h1 = *(const half8*)&xs[(size_t)s1 * 64 + seg * 8];
#pragma unroll
        for (int j = 0; j < 8; ++j) acc[j] += (float)h0[j] + (float)h1[j];
    }
    if (k < end) {
        int s0 = csr[k];
        half8 h0 = *(const half8*)&xs[(size_t)s0 * 64 + seg * 8];
#pragma unroll
        for (int j = 0; j < 8; ++j) acc[j] += (float)h0[j];
    }
#pragma unroll
    for (int j = 0; j < 8; ++j) acc[j] += __shfl_xor(acc[j], 8);
    if (slot == 0 && valid) {
        half8 o;
#pragma unroll
        for (int j = 0; j < 8; ++j) o[j] = (_Float16)((acc[j] + (float)hs[j]) * di);
        *(half8*)&agg[(size_t)node * 64 + seg * 8] = o;
    }
}

// Layer-2 gather fused with +b2, relu, and both Wc dot products.
__global__ __launch_bounds__(256) void k_gather2(const __half* __restrict__ ts,
                          const float* __restrict__ dinv,
                          const int* __restrict__ row_ptr, const int* __restrict__ csr,
                          const float* __restrict__ b2, const float* __restrict__ Wc,
                          float* __restrict__ s0o, float* __restrict__ s1o, int N) {
    int wv = threadIdx.x >> 6, l = threadIdx.x & 63;
    int ns = l >> 4;
    int slot = (l >> 3) & 1;
    int seg = l & 7;
    int node = (blockIdx.x * 4 + wv) * 4 + ns;
    bool valid = node < N;
    int nc = valid ? node : N - 1;
    int beg = row_ptr[nc];
    int end = valid ? row_ptr[nc + 1] : beg;
    float di = dinv[nc];
    half8 hs = *(const half8*)&ts[(size_t)nc * 64 + seg * 8];
    float acc[8];
#pragma unroll
    for (int j = 0; j < 8; ++j) acc[j] = 0.f;
    int k = beg + slot;
    for (; k + 2 < end; k += 4) {
        int s0 = csr[k], s1 = csr[k + 2];
        half8 h0 = *(const half8*)&ts[(size_t)s0 * 64 + seg * 8];
        half8 h1 = *(const half8*)&ts[(size_t)s1 * 64 + seg * 8];
#pragma unroll
        for (int j = 0; j < 8; ++j) acc[j] += (float)h0[j] + (float)h1[j];
    }
    if (k < end) {
        int s0 = csr[k];
        half8 h0 = *(const half8*)&ts[(size_t)s0 * 64 + seg * 8];
#pragma unroll
        for (int j = 0; j < 8; ++j) acc[j] += (float)h0[j];
    }
#pragma unroll
    for (int j = 0; j < 8; ++j) acc[j] += __shfl_xor(acc[j], 8);
    if (slot == 0) {
        float4 b2a = *(const float4*)&b2[seg * 8];
        float4 b2b = *(const float4*)&b2[seg * 8 + 4];
        float4 w0a = *(const float4*)&Wc[seg * 8];
        float4 w0b = *(const float4*)&Wc[seg * 8 + 4];
        float4 w1a = *(const float4*)&Wc[64 + seg * 8];
        float4 w1b = *(const float4*)&Wc[64 + seg * 8 + 4];
        float bb[8] = {b2a.x, b2a.y, b2a.z, b2a.w, b2b.x, b2b.y, b2b.z, b2b.w};
        float w0[8] = {w0a.x, w0a.y, w0a.z, w0a.w, w0b.x, w0b.y, w0b.z, w0b.w};
        float w1[8] = {w1a.x, w1a.y, w1a.z, w1a.w, w1b.x, w1b.y, w1b.z, w1b.w};
        float p0 = 0.f, p1 = 0.f;
#pragma unroll
        for (int j = 0; j < 8; ++j) {
            float v = fmaxf((acc[j] + (float)hs[j]) * di + bb[j], 0.f);
            p0 = fmaf(v, w0[j], p0);
            p1 = fmaf(v, w1[j], p1);
        }
        p0 += __shfl_xor(p0, 1); p1 += __shfl_xor(p1, 1);
        p0 += __shfl_xor(p0, 2); p1 += __shfl_xor(p1, 2);
        p0 += __shfl_xor(p0, 4); p1 += __shfl_xor(p1, 4);
        if (seg == 0 && valid) { s0o[node] = p0; s1o[node] = p1; }
    }
}

// ---------------------------------------------------------------------------
// MFMA fused MLP: ts = fp16( dinv * ( relu(agg @ W1 + b1) @ W2 ) ), row-major out
__global__ __launch_bounds__(256) void k_mlp_mfma(const __half* __restrict__ agg_h,
                                                  const __half* __restrict__ w1f,
                                                  const __half* __restrict__ w2f,
                                                  const float* __restrict__ b1,
                                                  const float* __restrict__ dinv,
                                                  __half* __restrict__ ts, int N) {
    __shared__ __align__(16) __half w1l[8192];
    __shared__ __align__(16) __half w2l[8192];
    {
        const float4* sA = (const float4*)w1f;
        const float4* sB = (const float4*)w2f;
        float4* dA = (float4*)w1l;
        float4* dB = (float4*)w2l;
        for (int i = threadIdx.x; i < 1024; i += 256) { dA[i] = sA[i]; dB[i] = sB[i]; }
    }
    __syncthreads();

    int wv = threadIdx.x >> 6, l = threadIdx.x & 63;
    int m0 = blockIdx.x * 64 + wv * 16;
    if (m0 >= N) return;
    int q = l >> 4, ml = l & 15;
    int rowA = m0 + ml; if (rowA >= N) rowA = N - 1;

    half8 bfr0 = *(const half8*)&agg_h[(size_t)rowA * 64 + q * 8];
    half8 bfr1 = *(const half8*)&agg_h[(size_t)rowA * 64 + 32 + q * 8];

    int pk[8][2];
#pragma unroll
    for (int nt = 0; nt < 8; ++nt) {
        float4 bb = *(const float4*)&b1[nt * 16 + q * 4];
        f32x4 cacc; cacc[0] = bb.x; cacc[1] = bb.y; cacc[2] = bb.z; cacc[3] = bb.w;
        half8 a0 = *(const half8*)&w1l[(nt * 2 + 0) * 512 + l * 8];
        cacc = __builtin_amdgcn_mfma_f32_16x16x32_f16(a0, bfr0, cacc, 0, 0, 0);
        half8 a1 = *(const half8*)&w1l[(nt * 2 + 1) * 512 + l * 8];
        cacc = __builtin_amdgcn_mfma_f32_16x16x32_f16(a1, bfr1, cacc, 0, 0, 0);
        union { __half2 h; int i; } u0, u1;
        u0.h = __floats2half2_rn(fmaxf(cacc[0], 0.f), fmaxf(cacc[1], 0.f));
        u1.h = __floats2half2_rn(fmaxf(cacc[2], 0.f), fmaxf(cacc[3], 0.f));
        pk[nt][0] = u0.i;
        pk[nt][1] = u1.i;
    }

    int src0 = ml + 16 * ((2 * q) & 3);
    int src1 = ml + 16 * ((2 * q + 1) & 3);
    bool hi = (q >= 2);
    half8 afr[4];
#pragma unroll
    for (int kc = 0; kc < 4; ++kc) {
        int t0 = 2 * kc, t1 = 2 * kc + 1;
        int d0a = __shfl(pk[t0][0], src0), d0b = __shfl(pk[t1][0], src0);
        int d1a = __shfl(pk[t0][1], src0), d1b = __shfl(pk[t1][1], src0);
        int d2a = __shfl(pk[t0][0], src1), d2b = __shfl(pk[t1][0], src1);
        int d3a = __shfl(pk[t0][1], src1), d3b = __shfl(pk[t1][1], src1);
        union { int d[4]; half8 h; } u;
        u.d[0] = hi ? d0b : d0a;
        u.d[1] = hi ? d1b : d1a;
        u.d[2] = hi ? d2b : d2a;
        u.d[3] = hi ? d3b : d3a;
        afr[kc] = u.h;
    }

    float dl = dinv[rowA];
    float dv[4];
#pragma unroll
    for (int r = 0; r < 4; ++r) dv[r] = __shfl(dl, q * 4 + r);

#pragma unroll
    for (int nt2 = 0; nt2 < 4; ++nt2) {
        f32x4 cacc; cacc[0] = 0.f; cacc[1] = 0.f; cacc[2] = 0.f; cacc[3] = 0.f;
#pragma unroll
        for (int kc = 0; kc < 4; ++kc) {
            half8 b = *(const half8*)&w2l[(nt2 * 4 + kc) * 512 + l * 8];
            cacc = __builtin_amdgcn_mfma_f32_16x16x32_f16(afr[kc], b, cacc, 0, 0, 0);
        }
#pragma unroll
        for (int r = 0; r < 4; ++r) {
            int node = m0 + q * 4 + r;
            if (node < N)
                ts[(size_t)node * 64 + nt2 * 16 + ml] = __float2half(cacc[r] * dv[r]);
        }
    }
}

__global__ void k_edge(const int* __restrict__ src, const int* __restrict__ dst,
                       const float* __restrict__ s0, const float* __restrict__ s1,
                       const float* __restrict__ bc, float* __restrict__ out, int E) {
    int e = blockIdx.x * blockDim.x + threadIdx.x;
    if (e >= E) return;
    float z = s0[src[e]] + s1[dst[e]] + bc[0];
    out[e] = 1.0f / (1.0f + expf(-z));
}

// ---------------------------------------------------------------------------
extern "C" void kernel_launch(void* const* d_in, const int* in_sizes, int n_in,
                              void* d_out, int out_size, void* d_ws, size_t ws_size,
                              hipStream_t stream) {
    const float* x  = (const float*)d_in[0];
    const unsigned int* eidx = (const unsigned int*)d_in[1];
    const float* W1 = (const float*)d_in[2];
    const float* b1 = (const float*)d_in[3];
    const float* W2 = (const float*)d_in[4];
    const float* b2 = (const float*)d_in[5];
    const float* Wc = (const float*)d_in[6];
    const float* bc = (const float*)d_in[7];
    float* out = (float*)d_out;

    int N = in_sizes[0] / IN_D;
    int E = in_sizes[1] / 2;
    int nbuk = (N + 511) >> 9;  // 196 buckets of 512 nodes (<= 256)

    char* p = (char*)d_ws;
    int*   src     = (int*)p;    p += (size_t)E * 4;
    int*   dst     = (int*)p;    p += (size_t)E * 4;
    int*   bkcnt   = (int*)p;    p += 256 * 4;
    int*   bkbase  = (int*)p;    p += 260 * 4;
    int*   bcur    = (int*)p;    p += 256 * 4;
    int*   row_ptr = (int*)p;    p += (size_t)(N + 1) * 4;
    int*   csr_src = (int*)p;    p += (size_t)E * 4;
    float* dinv    = (float*)p;  p += (size_t)N * 4;
    float* s0      = (float*)p;  p += (size_t)N * 4;
    float* s1      = (float*)p;  p += (size_t)N * 4;
    p += 15; p = (char*)((size_t)p & ~(size_t)15);
    int2*  pairs   = (int2*)p;   p += (size_t)E * 8;   // dead after k_build
    __half* xs    = (__half*)p;  p += (size_t)N * 64 * 2;
    __half* aggh  = (__half*)p;  p += (size_t)N * 64 * 2;
    __half* ts    = (__half*)p;  p += (size_t)N * 64 * 2;
    __half* w1f   = (__half*)p;  p += 8192 * 2;
    __half* w2f   = (__half*)p;  p += 8192 * 2;

    hipMemsetAsync(bkcnt, 0, 256 * 4, stream);

    // CSR build: decode + bucket hist, tiny bucket scan, partition, bucket build
    k_decode2<<<(E + DCHUNK - 1) / DCHUNK, 256, 0, stream>>>(eidx, E, src, dst, bkcnt);
    k_wconv<<<8, 256, 0, stream>>>(W1, W2, w1f, w2f);
    k_bkscan<<<1, 256, 0, stream>>>(bkcnt, bkbase, bcur, nbuk, E);
    k_part<<<(E + CHUNK - 1) / CHUNK, 256, 0, stream>>>(src, dst, bcur, pairs, E);
    k_build<<<nbuk, 256, 0, stream>>>(pairs, bkbase, row_ptr, csr_src, dinv, N, E, nbuk);

    // Pre-scaled fp16 features (row-major); layer-1 gather
    k_xconv<<<(N * 32 + 255) / 256, 256, 0, stream>>>(x, dinv, xs, N);
    k_gather1<<<(N + 15) / 16, 256, 0, stream>>>(xs, dinv, row_ptr, csr_src, aggh, N);

    // MFMA fused MLP
    k_mlp_mfma<<<(N + 63) / 64, 256, 0, stream>>>(aggh, w1f, w2f, b1, dinv, ts, N);

    // Layer-2 gather fused with b2/relu/Wc scores
    k_gather2<<<(N + 15) / 16, 256, 0, stream>>>(ts, dinv, row_ptr, csr_src,
                                                 b2, Wc, s0, s1, N);

    // Per-edge sigmoid from per-node partial scores
    k_edge<<<(E + 255) / 256, 256, 0, stream>>>(src, dst, s0, s1, bc, out, E);
}

// Round 3
// 230.700 us; speedup vs baseline: 1.2145x; 1.0090x over previous
//
#include <hip/hip_runtime.h>
#include <hip/hip_fp16.h>
#include <math.h>

#define IN_D 64
#define HID_D 128
#define OUT_D 64

typedef _Float16 half8 __attribute__((ext_vector_type(8)));
typedef float f32x4 __attribute__((ext_vector_type(4)));

// Per-bucket worst-case CSR padding slack: 512 nodes x max 7 pad entries.
#define BSLACK (512 * 7)

// ---------------------------------------------------------------------------
// Decode edge_index (robust to int32 or int64 storage) + LDS-privatized
// bucket histogram (bucket = dst>>9).
#define DCHUNK 2048
__global__ __launch_bounds__(256) void k_decode2(const unsigned int* __restrict__ raw,
                                                 int E,
                                                 int* __restrict__ src,
                                                 int* __restrict__ dst,
                                                 int* __restrict__ bkcnt) {
    __shared__ int hist[256];
    __shared__ int is64;
    if (threadIdx.x == 0) {
        int f = 1;
        for (int i = 1; i < 64; i += 2) f &= (raw[i] == 0u);
        is64 = f;
    }
    for (int i = threadIdx.x; i < 256; i += 256) hist[i] = 0;
    __syncthreads();
    int e0 = blockIdx.x * DCHUNK;
#pragma unroll
    for (int i = 0; i < 8; ++i) {
        int e = e0 + threadIdx.x + i * 256;
        if (e < E) {
            int s, d;
            if (is64) {
                s = (int)raw[2 * (size_t)e];
                d = (int)raw[2 * ((size_t)E + e)];
            } else {
                s = (int)raw[e];
                d = (int)raw[E + e];
            }
            src[e] = s;
            dst[e] = d;
            atomicAdd(&hist[d >> 9], 1);
        }
    }
    __syncthreads();
    if (hist[threadIdx.x] > 0)
        atomicAdd(&bkcnt[threadIdx.x], hist[threadIdx.x]);
}

// ---------------------------------------------------------------------------
// Tiny single-block exclusive scan of bucket counts -> bucket bases + cursors.
__global__ void k_bkscan(const int* __restrict__ bkcnt, int* __restrict__ bkbase,
                         int* __restrict__ bcur, int nbuk, int E) {
    int t = threadIdx.x;  // 256 threads, nbuk <= 256
    int v = (t < nbuk) ? bkcnt[t] : 0;
    int orig = v;
    int lane = t & 63, w = t >> 6;
    for (int off = 1; off < 64; off <<= 1) {
        int n = __shfl_up(v, off);
        if (lane >= off) v += n;
    }
    __shared__ int wsum[4];
    if (lane == 63) wsum[w] = v;
    __syncthreads();
    for (int k = 0; k < w; ++k) v += wsum[k];
    int base = v - orig;
    if (t < nbuk) { bkbase[t] = base; bcur[t] = base; }
    if (t == 0) bkbase[nbuk] = E;
}

// ---------------------------------------------------------------------------
// Phase A: partition edges into coarse dst-buckets (512 nodes each).
#define CHUNK 2048
__global__ __launch_bounds__(256) void k_part(const int* __restrict__ src,
                                              const int* __restrict__ dst,
                                              int* __restrict__ bcur,
                                              int2* __restrict__ pairs, int E) {
    __shared__ int hist[256];
    __shared__ int base[256];
    __shared__ int cnt[256];
    for (int i = threadIdx.x; i < 256; i += 256) { hist[i] = 0; cnt[i] = 0; }
    __syncthreads();
    int e0 = blockIdx.x * CHUNK;
    int s[8], d[8], b[8];
#pragma unroll
    for (int i = 0; i < 8; ++i) {
        int e = e0 + threadIdx.x + i * 256;
        if (e < E) {
            s[i] = src[e]; d[i] = dst[e]; b[i] = d[i] >> 9;
            atomicAdd(&hist[b[i]], 1);
        } else b[i] = -1;
    }
    __syncthreads();
    if (hist[threadIdx.x] > 0)
        base[threadIdx.x] = atomicAdd(&bcur[threadIdx.x], hist[threadIdx.x]);
    __syncthreads();
#pragma unroll
    for (int i = 0; i < 8; ++i) {
        if (b[i] >= 0) {
            int pos = base[b[i]] + atomicAdd(&cnt[b[i]], 1);
            pairs[pos] = make_int2(s[i], d[i]);
        }
    }
}

// ---------------------------------------------------------------------------
// Per-bucket padded-CSR build: LDS degree histogram -> scan of PADDED degrees
// (each node's list padded to a multiple of 8 with sentinel index N, which
// points at an all-zeros feature row). Gathers can then run an unconditional
// 4-wide load loop with no tail and no masks. Writes prowdeg = {pstart,pdeg}.
__global__ __launch_bounds__(256) void k_build(const int2* __restrict__ pairs,
                                               const int* __restrict__ bkbase,
                                               int2* __restrict__ prowdeg,
                                               int* __restrict__ csr_src,
                                               float* __restrict__ dinv,
                                               int N, int nbuk) {
    __shared__ int deg5[512];
    __shared__ int cur5[512];
    __shared__ int wsum[4];
    int b = blockIdx.x;
    int n0 = b << 9;
    int n1 = n0 + 512; if (n1 > N) n1 = N;
    int nn = n1 - n0;
    deg5[threadIdx.x] = 0;
    deg5[threadIdx.x + 256] = 0;
    __syncthreads();
    int beg = bkbase[b], end = bkbase[b + 1];
    for (int i = beg + threadIdx.x; i < end; i += 256)
        atomicAdd(&deg5[pairs[i].y - n0], 1);
    __syncthreads();
    // exclusive scan over 512 PADDED degrees, 2 elements per thread
    int pbase = beg + b * BSLACK;   // padded bucket base (disjoint regions)
    int t = threadIdx.x;
    int v0 = deg5[2 * t], v1 = deg5[2 * t + 1];
    int p0 = (v0 + 7) & ~7, p1 = (v1 + 7) & ~7;
    int s = p0 + p1;
    int lane = t & 63, w = t >> 6;
    int inc = s;
    for (int off = 1; off < 64; off <<= 1) {
        int n = __shfl_up(inc, off);
        if (lane >= off) inc += n;
    }
    if (lane == 63) wsum[w] = inc;
    __syncthreads();
    for (int k = 0; k < w; ++k) inc += wsum[k];
    int ex0 = inc - s;   // exclusive prefix of element 2t
    int ex1 = inc - p1;  // exclusive prefix of element 2t+1
    int ps0 = pbase + ex0, ps1 = pbase + ex1;
    cur5[2 * t]     = ps0;
    cur5[2 * t + 1] = ps1;
    if (2 * t < nn) {
        prowdeg[n0 + 2 * t] = make_int2(ps0, p0);
        dinv[n0 + 2 * t] = rsqrtf((float)v0 + 1.0f);  // +1 = self loop
    }
    if (2 * t + 1 < nn) {
        prowdeg[n0 + 2 * t + 1] = make_int2(ps1, p1);
        dinv[n0 + 2 * t + 1] = rsqrtf((float)v1 + 1.0f);
    }
    __syncthreads();
    // place real edges
    for (int i = beg + threadIdx.x; i < end; i += 256) {
        int2 r = pairs[i];
        int pos = atomicAdd(&cur5[r.y - n0], 1);
        csr_src[pos] = r.x;
    }
    __syncthreads();
    // sentinel-fill pad region of each node (cur5 now = pstart + real_deg)
    for (int i = cur5[2 * t]; i < ps0 + p0; ++i) csr_src[i] = N;
    for (int i = cur5[2 * t + 1]; i < ps1 + p1; ++i) csr_src[i] = N;
}

// ---------------------------------------------------------------------------
// xs[i,:] = fp16( dinv[i] * x[i,:] ), row-major; also zeroes the sentinel
// row N of both xs and ts (target of padded-CSR sentinel loads).
__global__ void k_xconv(const float* __restrict__ x, const float* __restrict__ dinv,
                        __half* __restrict__ xs, __half* __restrict__ ts, int N) {
    int idx = blockIdx.x * blockDim.x + threadIdx.x;
    if (idx >= (N + 1) * 32) return;
    int i = idx >> 5, c = (idx & 31) * 2;
    if (i == N) {
        *(__half2*)&xs[(size_t)i * 64 + c] = __floats2half2_rn(0.f, 0.f);
        *(__half2*)&ts[(size_t)i * 64 + c] = __floats2half2_rn(0.f, 0.f);
        return;
    }
    float di = dinv[i];
    float2 v = *(const float2*)&x[(size_t)i * 64 + c];
    *(__half2*)&xs[(size_t)i * 64 + c] = __floats2half2_rn(v.x * di, v.y * di);
}

// ---------------------------------------------------------------------------
// Pre-pack W1 (A-operand layout) and W2 (B-operand layout) into MFMA fragment order.
__global__ void k_wconv(const float* __restrict__ W1, const float* __restrict__ W2,
                        __half* __restrict__ w1f, __half* __restrict__ w2f) {
    int t = blockIdx.x * 256 + threadIdx.x;  // 0..2047
    if (t >= 2048) return;
    int which = t >> 10;
    int fl = t & 1023;
    int f = fl >> 6, l = fl & 63;
    int q = l >> 4, n16 = l & 15;
    if (which == 0) {
        int nt = f >> 1, kc = f & 1;
        int n = nt * 16 + n16;
        int k0 = kc * 32 + q * 8;
        for (int j = 0; j < 8; ++j)
            w1f[(size_t)fl * 8 + j] = __float2half(W1[(k0 + j) * 128 + n]);
    } else {
        int nt = f >> 2, kc = f & 3;
        int n = nt * 16 + n16;
        int k0 = kc * 32 + q * 8;
        for (int j = 0; j < 8; ++j)
            w2f[(size_t)fl * 8 + j] = __float2half(W2[(k0 + j) * 64 + n]);
    }
}

// ---------------------------------------------------------------------------
// Layer-1 gather: wave = 4 nodes x (2 slots x 8 col-segments). Padded CSR
// makes the main loop unconditional: 4 independent row loads per slot-stream
// per iteration (32 rows in flight per wave), no tail, no masks. Sentinel
// rows (index N) are all-zero and L1-hot.
__global__ __launch_bounds__(256) void k_gather1(const __half* __restrict__ xs,
                          const float* __restrict__ dinv,
                          const int2* __restrict__ prowdeg, const int* __restrict__ csr,
                          __half* __restrict__ agg, int N) {
    int wv = threadIdx.x >> 6, l = threadIdx.x & 63;
    int ns = l >> 4;           // node-sub 0..3
    int slot = (l >> 3) & 1;   // 0..1
    int seg = l & 7;           // 0..7
    int node = (blockIdx.x * 4 + wv) * 4 + ns;
    bool valid = node < N;
    int nc = valid ? node : N - 1;
    int2 rp = prowdeg[nc];
    int beg = rp.x;
    int pend = beg + (valid ? rp.y : 0);
    float di = dinv[nc];
    half8 hs = *(const half8*)&xs[(size_t)nc * 64 + seg * 8];
    float acc[8];
#pragma unroll
    for (int j = 0; j < 8; ++j) acc[j] = 0.f;
    for (int k = beg + slot; k < pend; k += 8) {
        int s0 = csr[k], s1 = csr[k + 2], s2 = csr[k + 4], s3 = csr[k + 6];
        half8 h0 = *(const half8*)&xs[(size_t)s0 * 64 + seg * 8];
        half8 h1 = *(const half8*)&xs[(size_t)s1 * 64 + seg * 8];
        half8 h2 = *(const half8*)&xs[(size_t)s2 * 64 + seg * 8];
        half8 h3 = *(const half8*)&xs[(size_t)s3 * 64 + seg * 8];
#pragma unroll
        for (int j = 0; j < 8; ++j) {
            float t01 = (float)h0[j] + (float)h1[j];
            float t23 = (float)h2[j] + (float)h3[j];
            acc[j] += t01 + t23;
        }
    }
#pragma unroll
    for (int j = 0; j < 8; ++j) acc[j] += __shfl_xor(acc[j], 8);
    if (slot == 0 && valid) {
        half8 o;
#pragma unroll
        for (int j = 0; j < 8; ++j) o[j] = (_Float16)((acc[j] + (float)hs[j]) * di);
        *(half8*)&agg[(size_t)node * 64 + seg * 8] = o;
    }
}

// Layer-2 gather fused with +b2, relu, and both Wc dot products.
__global__ __launch_bounds__(256) void k_gather2(const __half* __restrict__ ts,
                          const float* __restrict__ dinv,
                          const int2* __restrict__ prowdeg, const int* __restrict__ csr,
                          const float* __restrict__ b2, const float* __restrict__ Wc,
                          float* __restrict__ s0o, float* __restrict__ s1o, int N) {
    int wv = threadIdx.x >> 6, l = threadIdx.x & 63;
    int ns = l >> 4;
    int slot = (l >> 3) & 1;
    int seg = l & 7;
    int node = (blockIdx.x * 4 + wv) * 4 + ns;
    bool valid = node < N;
    int nc = valid ? node : N - 1;
    int2 rp = prowdeg[nc];
    int beg = rp.x;
    int pend = beg + (valid ? rp.y : 0);
    float di = dinv[nc];
    half8 hs = *(const half8*)&ts[(size_t)nc * 64 + seg * 8];
    float acc[8];
#pragma unroll
    for (int j = 0; j < 8; ++j) acc[j] = 0.f;
    for (int k = beg + slot; k < pend; k += 8) {
        int s0 = csr[k], s1 = csr[k + 2], s2 = csr[k + 4], s3 = csr[k + 6];
        half8 h0 = *(const half8*)&ts[(size_t)s0 * 64 + seg * 8];
        half8 h1 = *(const half8*)&ts[(size_t)s1 * 64 + seg * 8];
        half8 h2 = *(const half8*)&ts[(size_t)s2 * 64 + seg * 8];
        half8 h3 = *(const half8*)&ts[(size_t)s3 * 64 + seg * 8];
#pragma unroll
        for (int j = 0; j < 8; ++j) {
            float t01 = (float)h0[j] + (float)h1[j];
            float t23 = (float)h2[j] + (float)h3[j];
            acc[j] += t01 + t23;
        }
    }
#pragma unroll
    for (int j = 0; j < 8; ++j) acc[j] += __shfl_xor(acc[j], 8);
    if (slot == 0) {
        float4 b2a = *(const float4*)&b2[seg * 8];
        float4 b2b = *(const float4*)&b2[seg * 8 + 4];
        float4 w0a = *(const float4*)&Wc[seg * 8];
        float4 w0b = *(const float4*)&Wc[seg * 8 + 4];
        float4 w1a = *(const float4*)&Wc[64 + seg * 8];
        float4 w1b = *(const float4*)&Wc[64 + seg * 8 + 4];
        float bb[8] = {b2a.x, b2a.y, b2a.z, b2a.w, b2b.x, b2b.y, b2b.z, b2b.w};
        float w0[8] = {w0a.x, w0a.y, w0a.z, w0a.w, w0b.x, w0b.y, w0b.z, w0b.w};
        float w1[8] = {w1a.x, w1a.y, w1a.z, w1a.w, w1b.x, w1b.y, w1b.z, w1b.w};
        float p0 = 0.f, p1 = 0.f;
#pragma unroll
        for (int j = 0; j < 8; ++j) {
            float v = fmaxf((acc[j] + (float)hs[j]) * di + bb[j], 0.f);
            p0 = fmaf(v, w0[j], p0);
            p1 = fmaf(v, w1[j], p1);
        }
        p0 += __shfl_xor(p0, 1); p1 += __shfl_xor(p1, 1);
        p0 += __shfl_xor(p0, 2); p1 += __shfl_xor(p1, 2);
        p0 += __shfl_xor(p0, 4); p1 += __shfl_xor(p1, 4);
        if (seg == 0 && valid) { s0o[node] = p0; s1o[node] = p1; }
    }
}

// ---------------------------------------------------------------------------
// MFMA fused MLP: ts = fp16( dinv * ( relu(agg @ W1 + b1) @ W2 ) ), row-major out
__global__ __launch_bounds__(256) void k_mlp_mfma(const __half* __restrict__ agg_h,
                                                  const __half* __restrict__ w1f,
                                                  const __half* __restrict__ w2f,
                                                  const float* __restrict__ b1,
                                                  const float* __restrict__ dinv,
                                                  __half* __restrict__ ts, int N) {
    __shared__ __align__(16) __half w1l[8192];
    __shared__ __align__(16) __half w2l[8192];
    {
        const float4* sA = (const float4*)w1f;
        const float4* sB = (const float4*)w2f;
        float4* dA = (float4*)w1l;
        float4* dB = (float4*)w2l;
        for (int i = threadIdx.x; i < 1024; i += 256) { dA[i] = sA[i]; dB[i] = sB[i]; }
    }
    __syncthreads();

    int wv = threadIdx.x >> 6, l = threadIdx.x & 63;
    int m0 = blockIdx.x * 64 + wv * 16;
    if (m0 >= N) return;
    int q = l >> 4, ml = l & 15;
    int rowA = m0 + ml; if (rowA >= N) rowA = N - 1;

    half8 bfr0 = *(const half8*)&agg_h[(size_t)rowA * 64 + q * 8];
    half8 bfr1 = *(const half8*)&agg_h[(size_t)rowA * 64 + 32 + q * 8];

    int pk[8][2];
#pragma unroll
    for (int nt = 0; nt < 8; ++nt) {
        float4 bb = *(const float4*)&b1[nt * 16 + q * 4];
        f32x4 cacc; cacc[0] = bb.x; cacc[1] = bb.y; cacc[2] = bb.z; cacc[3] = bb.w;
        half8 a0 = *(const half8*)&w1l[(nt * 2 + 0) * 512 + l * 8];
        cacc = __builtin_amdgcn_mfma_f32_16x16x32_f16(a0, bfr0, cacc, 0, 0, 0);
        half8 a1 = *(const half8*)&w1l[(nt * 2 + 1) * 512 + l * 8];
        cacc = __builtin_amdgcn_mfma_f32_16x16x32_f16(a1, bfr1, cacc, 0, 0, 0);
        union { __half2 h; int i; } u0, u1;
        u0.h = __floats2half2_rn(fmaxf(cacc[0], 0.f), fmaxf(cacc[1], 0.f));
        u1.h = __floats2half2_rn(fmaxf(cacc[2], 0.f), fmaxf(cacc[3], 0.f));
        pk[nt][0] = u0.i;
        pk[nt][1] = u1.i;
    }

    int src0 = ml + 16 * ((2 * q) & 3);
    int src1 = ml + 16 * ((2 * q + 1) & 3);
    bool hi = (q >= 2);
    half8 afr[4];
#pragma unroll
    for (int kc = 0; kc < 4; ++kc) {
        int t0 = 2 * kc, t1 = 2 * kc + 1;
        int d0a = __shfl(pk[t0][0], src0), d0b = __shfl(pk[t1][0], src0);
        int d1a = __shfl(pk[t0][1], src0), d1b = __shfl(pk[t1][1], src0);
        int d2a = __shfl(pk[t0][0], src1), d2b = __shfl(pk[t1][0], src1);
        int d3a = __shfl(pk[t0][1], src1), d3b = __shfl(pk[t1][1], src1);
        union { int d[4]; half8 h; } u;
        u.d[0] = hi ? d0b : d0a;
        u.d[1] = hi ? d1b : d1a;
        u.d[2] = hi ? d2b : d2a;
        u.d[3] = hi ? d3b : d3a;
        afr[kc] = u.h;
    }

    float dl = dinv[rowA];
    float dv[4];
#pragma unroll
    for (int r = 0; r < 4; ++r) dv[r] = __shfl(dl, q * 4 + r);

#pragma unroll
    for (int nt2 = 0; nt2 < 4; ++nt2) {
        f32x4 cacc; cacc[0] = 0.f; cacc[1] = 0.f; cacc[2] = 0.f; cacc[3] = 0.f;
#pragma unroll
        for (int kc = 0; kc < 4; ++kc) {
            half8 b = *(const half8*)&w2l[(nt2 * 4 + kc) * 512 + l * 8];
            cacc = __builtin_amdgcn_mfma_f32_16x16x32_f16(afr[kc], b, cacc, 0, 0, 0);
        }
#pragma unroll
        for (int r = 0; r < 4; ++r) {
            int node = m0 + q * 4 + r;
            if (node < N)
                ts[(size_t)node * 64 + nt2 * 16 + ml] = __float2half(cacc[r] * dv[r]);
        }
    }
}

// Per-edge sigmoid, 2 edges per thread, fast exp.
__global__ void k_edge(const int* __restrict__ src, const int* __restrict__ dst,
                       const float* __restrict__ s0, const float* __restrict__ s1,
                       const float* __restrict__ bc, float* __restrict__ out, int E) {
    int e = (blockIdx.x * blockDim.x + threadIdx.x) * 2;
    if (e >= E) return;
    float b = bc[0];
    if (e + 1 < E) {
        int2 sv = *(const int2*)&src[e];
        int2 dv = *(const int2*)&dst[e];
        float z0 = s0[sv.x] + s1[dv.x] + b;
        float z1 = s0[sv.y] + s1[dv.y] + b;
        float2 o;
        o.x = 1.0f / (1.0f + __expf(-z0));
        o.y = 1.0f / (1.0f + __expf(-z1));
        *(float2*)&out[e] = o;
    } else {
        float z = s0[src[e]] + s1[dst[e]] + b;
        out[e] = 1.0f / (1.0f + __expf(-z));
    }
}

// ---------------------------------------------------------------------------
extern "C" void kernel_launch(void* const* d_in, const int* in_sizes, int n_in,
                              void* d_out, int out_size, void* d_ws, size_t ws_size,
                              hipStream_t stream) {
    const float* x  = (const float*)d_in[0];
    const unsigned int* eidx = (const unsigned int*)d_in[1];
    const float* W1 = (const float*)d_in[2];
    const float* b1 = (const float*)d_in[3];
    const float* W2 = (const float*)d_in[4];
    const float* b2 = (const float*)d_in[5];
    const float* Wc = (const float*)d_in[6];
    const float* bc = (const float*)d_in[7];
    float* out = (float*)d_out;

    int N = in_sizes[0] / IN_D;
    int E = in_sizes[1] / 2;
    int nbuk = (N + 511) >> 9;  // 196 buckets of 512 nodes (<= 256)
    size_t csr_cap = (size_t)E + (size_t)nbuk * BSLACK;

    char* p = (char*)d_ws;
    int*   src     = (int*)p;    p += (size_t)E * 4;
    int*   dst     = (int*)p;    p += (size_t)E * 4;
    int*   bkcnt   = (int*)p;    p += 256 * 4;
    int*   bkbase  = (int*)p;    p += 260 * 4;
    int*   bcur    = (int*)p;    p += 256 * 4;
    int*   csr_src = (int*)p;    p += csr_cap * 4;
    float* dinv    = (float*)p;  p += (size_t)N * 4;
    float* s0      = (float*)p;  p += (size_t)N * 4;
    float* s1      = (float*)p;  p += (size_t)N * 4;
    p += 15; p = (char*)((size_t)p & ~(size_t)15);
    int2*  prowdeg = (int2*)p;   p += (size_t)N * 8;
    int2*  pairs   = (int2*)p;   p += (size_t)E * 8;   // dead after k_build
    __half* xs    = (__half*)p;  p += (size_t)(N + 1) * 64 * 2;
    __half* aggh  = (__half*)p;  p += (size_t)N * 64 * 2;
    __half* ts    = (__half*)p;  p += (size_t)(N + 1) * 64 * 2;
    __half* w1f   = (__half*)p;  p += 8192 * 2;
    __half* w2f   = (__half*)p;  p += 8192 * 2;

    hipMemsetAsync(bkcnt, 0, 256 * 4, stream);

    // CSR build: decode + bucket hist, tiny bucket scan, partition, padded build
    k_decode2<<<(E + DCHUNK - 1) / DCHUNK, 256, 0, stream>>>(eidx, E, src, dst, bkcnt);
    k_wconv<<<8, 256, 0, stream>>>(W1, W2, w1f, w2f);
    k_bkscan<<<1, 256, 0, stream>>>(bkcnt, bkbase, bcur, nbuk, E);
    k_part<<<(E + CHUNK - 1) / CHUNK, 256, 0, stream>>>(src, dst, bcur, pairs, E);
    k_build<<<nbuk, 256, 0, stream>>>(pairs, bkbase, prowdeg, csr_src, dinv, N, nbuk);

    // Pre-scaled fp16 features (+ sentinel zero rows); layer-1 gather
    k_xconv<<<((N + 1) * 32 + 255) / 256, 256, 0, stream>>>(x, dinv, xs, ts, N);
    k_gather1<<<(N + 15) / 16, 256, 0, stream>>>(xs, dinv, prowdeg, csr_src, aggh, N);

    // MFMA fused MLP
    k_mlp_mfma<<<(N + 63) / 64, 256, 0, stream>>>(aggh, w1f, w2f, b1, dinv, ts, N);

    // Layer-2 gather fused with b2/relu/Wc scores
    k_gather2<<<(N + 15) / 16, 256, 0, stream>>>(ts, dinv, prowdeg, csr_src,
                                                 b2, Wc, s0, s1, N);

    // Per-edge sigmoid from per-node partial scores
    k_edge<<<(E / 2 + 255) / 256, 256, 0, stream>>>(src, dst, s0, s1, bc, out, E);
}